// Round 5
// baseline (1368.390 us; speedup 1.0000x reference)
//
#include <hip/hip_runtime.h>
#include <cstddef>
#include <cstdint>

// ---------------------------------------------------------------------------
// N=50000 nodes, E=1,650,000 edges (incl. self loops). Stages (in,out):
// (512,384),(384,256),(256,128), FC 128->128.
// fp16 activations/weights, fp32 accumulation everywhere.
// GEMM-first restructuring: (A h) W^T == A (h W^T); row scales commute.
// CSR rows padded to multiple of 4 edges; dummy edges target row Mpad of Z,
// which the GEMM NEVER writes (m < Mpad guard) and which is explicitly
// zeroed per stage. (R4 bug: dummy row N was GEMM-written from stale-junk
// pad input when the buffer stride changed between stages.)
// ---------------------------------------------------------------------------

typedef _Float16 h8 __attribute__((ext_vector_type(8)));
typedef _Float16 h4 __attribute__((ext_vector_type(4)));
typedef float f32x4 __attribute__((ext_vector_type(4)));

#define GLD_LDS16(gptr, lptr)                                                  \
  __builtin_amdgcn_global_load_lds(                                            \
      (const __attribute__((address_space(1))) void*)(gptr),                   \
      (__attribute__((address_space(3))) void*)(lptr), 16, 0, 0)

// ---------------- degree / CSR build ----------------

__global__ __launch_bounds__(256) void deg_kernel(
    const int* __restrict__ src, const int* __restrict__ dst,
    int* __restrict__ in_deg, int* __restrict__ out_deg, int E) {
  int e = blockIdx.x * 256 + threadIdx.x;
  if (e < E) {
    atomicAdd(&in_deg[dst[e]], 1);
    atomicAdd(&out_deg[src[e]], 1);
  }
}

// exclusive scan of PADDED degrees (round up to 4) -> row_ptr
__global__ __launch_bounds__(1024) void scan_kernel(
    const int* __restrict__ deg, int* __restrict__ row_ptr, int n) {
  __shared__ int buf[1024];
  __shared__ int carry_s;
  if (threadIdx.x == 0) carry_s = 0;
  __syncthreads();
  for (int base = 0; base < n; base += 1024) {
    int i = base + (int)threadIdx.x;
    int v = (i < n) ? ((deg[i] + 3) & ~3) : 0;
    buf[threadIdx.x] = v;
    __syncthreads();
    #pragma unroll
    for (int off = 1; off < 1024; off <<= 1) {
      int t = 0;
      if ((int)threadIdx.x >= off) t = buf[threadIdx.x - off];
      __syncthreads();
      buf[threadIdx.x] += t;
      __syncthreads();
    }
    int incl  = buf[threadIdx.x];
    int carry = carry_s;
    int total = buf[1023];
    __syncthreads();
    if (i < n) row_ptr[i] = carry + incl - v;
    if (threadIdx.x == 0) carry_s = carry + total;
    __syncthreads();
  }
  if (threadIdx.x == 0) row_ptr[n] = carry_s;
}

__global__ __launch_bounds__(256) void scatter_kernel(
    const int* __restrict__ src, const int* __restrict__ dst,
    const int* __restrict__ row_ptr, int* __restrict__ cnt,
    int* __restrict__ csr, int E) {
  int e = blockIdx.x * 256 + threadIdx.x;
  if (e < E) {
    int d = dst[e];
    int pos = row_ptr[d] + atomicAdd(&cnt[d], 1);
    csr[pos] = src[e];
  }
}

// fill padded tail of each row with dummy node id (zero Z row)
__global__ __launch_bounds__(256) void pad_fill_kernel(
    const int* __restrict__ row_ptr, const int* __restrict__ deg,
    int* __restrict__ csr, int n, int dummy) {
  int i = blockIdx.x * 256 + threadIdx.x;
  if (i < n) {
    int s = row_ptr[i] + deg[i], e = row_ptr[i + 1];
    for (int p = s; p < e; ++p) csr[p] = dummy;
  }
}

__global__ __launch_bounds__(256) void scaler_kernel(
    const int* __restrict__ in_deg, const int* __restrict__ out_deg,
    float* __restrict__ inv_src, float* __restrict__ inv_dst,
    float* __restrict__ inv_den, int n) {
  int i = blockIdx.x * 256 + threadIdx.x;
  if (i < n) {
    float od = (float)out_deg[i];
    float id = (float)in_deg[i];
    inv_src[i] = rsqrtf(od > 0.f ? od : 1.0f);
    inv_dst[i] = rsqrtf(id > 0.f ? id : 1.0f);
    inv_den[i] = 1.0f / (id + 1.0f);
  }
}

// ---------------- fp32 -> fp16 conversion (pad region zeroed) ----------------

__global__ __launch_bounds__(256) void cvt_kernel(
    const float* __restrict__ in, _Float16* __restrict__ out,
    long n_in, long n_pad) {
  long i = ((long)blockIdx.x * 256 + (long)threadIdx.x) * 4;
  if (i >= n_pad) return;
  float4 v = (i < n_in) ? *(const float4*)(in + i) : make_float4(0.f, 0.f, 0.f, 0.f);
  h4 h = {(_Float16)v.x, (_Float16)v.y, (_Float16)v.z, (_Float16)v.w};
  *(h4*)(out + i) = h;
}

// ---------------- fp16 MFMA GEMM: C[M x Nc] = A[M x K] @ W^T ----------------
// global_load_lds(16B) staging (m97 pattern): wave w DMAs A rows
// [16w,16w+16) and [64+16w,..), lane l -> row +l/4, col halves (l&3)*8;
// LDS dest = wave-uniform base + lane*16B == row-major 128x32-half tile.
// 4 waves 2x2, 64x64/wave, 16x16x32_f16, BK=32.
// A/B frag lane l: idx=l&15, k=(l>>4)*8+j; C/D: col=l&15, row=(l>>4)*4+reg.

template <typename OutT>
__global__ __launch_bounds__(256) void hgemm(
    const _Float16* __restrict__ A, const _Float16* __restrict__ W,
    OutT* __restrict__ C, int Mstore, int K, int Nc,
    const float* __restrict__ row_scale, const float* __restrict__ bias) {
  __shared__ _Float16 As[128 * 32];
  __shared__ _Float16 Bs[128 * 32];
  const int tid = threadIdx.x;
  const int bm = blockIdx.x * 128, bn = blockIdx.y * 128;
  const int wave = tid >> 6, lane = tid & 63;
  const int wm = (wave & 1) * 64, wn = (wave >> 1) * 64;
  const int lrow = lane & 15, lq = lane >> 4;

  const int colh = (lane & 3) * 8;             // 16B column chunk
  const int arow = wave * 16 + (lane >> 2);    // 0..63
  const _Float16* Ag  = A + (size_t)(bm + arow) * K + colh;
  const _Float16* Ag2 = A + (size_t)(bm + 64 + arow) * K + colh;
  const _Float16* Wg  = W + (size_t)(bn + arow) * K + colh;
  const _Float16* Wg2 = W + (size_t)(bn + 64 + arow) * K + colh;
  _Float16* lA  = As + wave * 512;             // wave-uniform LDS bases
  _Float16* lA2 = As + 64 * 32 + wave * 512;
  _Float16* lB  = Bs + wave * 512;
  _Float16* lB2 = Bs + 64 * 32 + wave * 512;

  f32x4 acc[4][4];
  #pragma unroll
  for (int i = 0; i < 4; ++i)
    #pragma unroll
    for (int j = 0; j < 4; ++j) acc[i][j] = (f32x4){0.f, 0.f, 0.f, 0.f};

  for (int k0 = 0; k0 < K; k0 += 32) {
    __syncthreads();  // prior iter's LDS reads complete before DMA overwrite
    GLD_LDS16(Ag + k0, lA);
    GLD_LDS16(Ag2 + k0, lA2);
    GLD_LDS16(Wg + k0, lB);
    GLD_LDS16(Wg2 + k0, lB2);
    __syncthreads();  // drains vmcnt: DMA visible to all waves
    h8 af[4], bf[4];
    #pragma unroll
    for (int i = 0; i < 4; ++i)
      af[i] = *(const h8*)(As + (wm + i * 16 + lrow) * 32 + lq * 8);
    #pragma unroll
    for (int j = 0; j < 4; ++j)
      bf[j] = *(const h8*)(Bs + (wn + j * 16 + lrow) * 32 + lq * 8);
    #pragma unroll
    for (int i = 0; i < 4; ++i)
      #pragma unroll
      for (int j = 0; j < 4; ++j)
        acc[i][j] = __builtin_amdgcn_mfma_f32_16x16x32_f16(af[i], bf[j], acc[i][j], 0, 0, 0);
  }

  #pragma unroll
  for (int i = 0; i < 4; ++i) {
    #pragma unroll
    for (int r = 0; r < 4; ++r) {
      const int m = bm + wm + i * 16 + lq * 4 + r;
      if (m < Mstore) {
        const float rsc = row_scale ? row_scale[m] : 1.0f;
        OutT* crow = C + (size_t)m * Nc + bn + wn + lrow;
        #pragma unroll
        for (int j = 0; j < 4; ++j) {
          float v = acc[i][j][r] * rsc;
          if (bias) v += bias[bn + wn + j * 16 + lrow];
          crow[j * 16] = (OutT)v;
        }
      }
    }
  }
}

// ---------------- CSR aggregation, fp16 gather / fp32 accumulate ----------------
// Rows padded to multiple of 4 edges (dummies hit zero row Mpad). Edge loop
// unrolled x4 -> 4*NV independent 16B loads in flight per lane.

template <int D, bool SELF>
__global__ __launch_bounds__(256) void agg_h(
    const _Float16* __restrict__ Z, const int* __restrict__ row_ptr,
    const int* __restrict__ csr, const float* __restrict__ out_scale,
    const float* __restrict__ bias, _Float16* __restrict__ out, int n) {
  constexpr int GROUP = 16;
  constexpr int NV = D / 8 / GROUP;  // 16B chunks per lane (3/2/1)
  const int gid = threadIdx.x >> 4;
  const int lane = threadIdx.x & 15;
  const int node = blockIdx.x * 16 + gid;
  if (node >= n) return;

  const int rs = row_ptr[node], re = row_ptr[node + 1];  // len % 4 == 0

  float acc[NV][8];
  #pragma unroll
  for (int v = 0; v < NV; ++v)
    #pragma unroll
    for (int q = 0; q < 8; ++q) acc[v][q] = 0.f;

  for (int e = rs; e < re; e += GROUP) {
    int m = re - e; if (m > GROUP) m = GROUP;      // m in {4,8,12,16}
    int eid = (e + lane < re) ? csr[e + lane] : 0;
    for (int j = 0; j < m; j += 4) {
      const int s0 = __shfl(eid, j + 0, GROUP);
      const int s1 = __shfl(eid, j + 1, GROUP);
      const int s2 = __shfl(eid, j + 2, GROUP);
      const int s3 = __shfl(eid, j + 3, GROUP);
      const h8* z0 = (const h8*)(Z + (size_t)s0 * D);
      const h8* z1 = (const h8*)(Z + (size_t)s1 * D);
      const h8* z2 = (const h8*)(Z + (size_t)s2 * D);
      const h8* z3 = (const h8*)(Z + (size_t)s3 * D);
      h8 t0[NV], t1[NV], t2[NV], t3[NV];
      #pragma unroll
      for (int v = 0; v < NV; ++v) {
        const int idx = lane + v * GROUP;
        t0[v] = z0[idx]; t1[v] = z1[idx]; t2[v] = z2[idx]; t3[v] = z3[idx];
      }
      #pragma unroll
      for (int v = 0; v < NV; ++v)
        #pragma unroll
        for (int q = 0; q < 8; ++q)
          acc[v][q] += ((float)t0[v][q] + (float)t1[v][q]) +
                       ((float)t2[v][q] + (float)t3[v][q]);
    }
  }

  const float osc = out_scale[node];
  const h8* zs = (const h8*)(Z + (size_t)node * D);
  _Float16* orow = out + (size_t)node * D;
  #pragma unroll
  for (int v = 0; v < NV; ++v) {
    const int idx = lane + v * GROUP;
    if (SELF) {
      h8 t = zs[idx];
      #pragma unroll
      for (int q = 0; q < 8; ++q) acc[v][q] += (float)t[q];
    }
    h8 r;
    #pragma unroll
    for (int q = 0; q < 8; ++q) {
      float x = acc[v][q] * osc + bias[idx * 8 + q];
      r[q] = (_Float16)fmaxf(x, 0.f);
    }
    *(h8*)(orow + idx * 8) = r;
  }
}

// ---------------- host-side orchestration ----------------

static void launch_cvt(const float* in, _Float16* out, long n_in, long n_pad,
                       hipStream_t st) {
  long thr = n_pad / 4;
  cvt_kernel<<<(int)((thr + 255) / 256), 256, 0, st>>>(in, out, n_in, n_pad);
}

extern "C" void kernel_launch(void* const* d_in, const int* in_sizes, int n_in,
                              void* d_out, int out_size, void* d_ws, size_t ws_size,
                              hipStream_t stream) {
  const float* features = (const float*)d_in[0];
  const int*   src      = (const int*)d_in[1];
  const int*   dst      = (const int*)d_in[2];
  const float* wsrc[7] = {(const float*)d_in[3],  (const float*)d_in[5],
                          (const float*)d_in[7],  (const float*)d_in[9],
                          (const float*)d_in[11], (const float*)d_in[13],
                          (const float*)d_in[15]};  // sw0,gw0,sw1,gw1,sw2,gw2,fc
  const float* sb[3] = {(const float*)d_in[4],  (const float*)d_in[8],  (const float*)d_in[12]};
  const float* gb[3] = {(const float*)d_in[6],  (const float*)d_in[10], (const float*)d_in[14]};
  const float* fc_b  = (const float*)d_in[16];

  const int N = in_sizes[0] / 512;
  const int E = in_sizes[1];
  const int MB = (N + 127) / 128;
  const int Mpad = MB * 128;
  const int Epad_max = E + 3 * N + 64;

  const int wcnt[7] = {384 * 512, 384 * 384, 256 * 384, 256 * 256,
                       128 * 256, 128 * 128, 128 * 128};

  // workspace layout (fp16 buffers first, 16B-aligned throughout)
  char* ws = (char*)d_ws;
  _Float16* featH = (_Float16*)ws;                       // Mpad*512
  _Float16* hA    = featH + (size_t)Mpad * 512;          // Mpad*384 (activations)
  _Float16* hB    = hA + (size_t)Mpad * 384;             // (Mpad+1)*384 (Z + dummy row)
  _Float16* wH[7];
  {
    _Float16* p = hB + (size_t)(Mpad + 1) * 384;
    for (int i = 0; i < 7; ++i) { wH[i] = p; p += wcnt[i]; }
  }
  int* csr     = (int*)(wH[6] + wcnt[6]);                // Epad_max ints
  int* rp      = csr + Epad_max;                         // N+1
  int* in_dg   = rp + (N + 1);                           // N (zeroed)
  int* out_dg  = in_dg + N;                              // N (zeroed)
  int* cnt     = out_dg + N;                             // N (zeroed)
  float* inv_src = (float*)(cnt + N);                    // N (GEMM pad-row OOB
  float* inv_dst = inv_src + N;                          // N  scale reads land
  float* inv_den = inv_dst + N;                          // N  here: finite)

  size_t totw = 0; for (int i = 0; i < 7; ++i) totw += wcnt[i];
  size_t needed = ((size_t)Mpad * (512 + 384) + (size_t)(Mpad + 1) * 384 + totw) * 2 +
                  ((size_t)Epad_max + (N + 1) + 6 * (size_t)N) * 4;
  if (ws_size < needed) return;

  (void)hipMemsetAsync(in_dg, 0, sizeof(int) * 3 * (size_t)N, stream);
  // keep hA pad rows zero (defensive: GEMM A-tile junk stays bounded)
  (void)hipMemsetAsync(hA + (size_t)N * 384, 0, (size_t)(Mpad - N) * 384 * 2, stream);

  const int eb = (E + 255) / 256;
  const int nb = (N + 255) / 256;
  deg_kernel<<<eb, 256, 0, stream>>>(src, dst, in_dg, out_dg, E);
  scan_kernel<<<1, 1024, 0, stream>>>(in_dg, rp, N);
  scatter_kernel<<<eb, 256, 0, stream>>>(src, dst, rp, cnt, csr, E);
  pad_fill_kernel<<<nb, 256, 0, stream>>>(rp, in_dg, csr, N, Mpad);  // dummy = Mpad
  scaler_kernel<<<nb, 256, 0, stream>>>(in_dg, out_dg, inv_src, inv_dst, inv_den, N);

  // conversions (featH pad rows zeroed by cvt)
  launch_cvt(features, featH, (long)N * 512, (long)Mpad * 512, stream);
  for (int i = 0; i < 7; ++i) launch_cvt(wsrc[i], wH[i], wcnt[i], wcnt[i], stream);

  const int dout[3] = {384, 256, 128};
  const _Float16* h = featH;
  int K = 512;
  for (int s = 0; s < 3; ++s) {
    const int D = dout[s];
    dim3 gg(MB, D / 128);
    const int ab = (N + 15) / 16;
    // zero the dummy row (row Mpad at stride D) for this stage; the GEMM
    // never writes row Mpad, but earlier stages' wider-stride writes covered
    // these bytes, so re-zero each stage.
    (void)hipMemsetAsync(hB + (size_t)Mpad * D, 0, (size_t)D * 2, stream);
    // SAGE: Z = h @ sw^T ; h' = relu((sum_in Z + Z_self)*inv_den + sb)
    hgemm<_Float16><<<gg, 256, 0, stream>>>(h, wH[2 * s], hB, Mpad, K, D, nullptr, nullptr);
    if (D == 384)      agg_h<384, true><<<ab, 256, 0, stream>>>(hB, rp, csr, inv_den, sb[s], hA, N);
    else if (D == 256) agg_h<256, true><<<ab, 256, 0, stream>>>(hB, rp, csr, inv_den, sb[s], hA, N);
    else               agg_h<128, true><<<ab, 256, 0, stream>>>(hB, rp, csr, inv_den, sb[s], hA, N);
    // GraphConv: Z = (h'*inv_src) @ gw^T ; h'' = relu((sum_in Z)*inv_dst + gb)
    hgemm<_Float16><<<gg, 256, 0, stream>>>(hA, wH[2 * s + 1], hB, Mpad, D, D, inv_src, nullptr);
    if (D == 384)      agg_h<384, false><<<ab, 256, 0, stream>>>(hB, rp, csr, inv_dst, gb[s], hA, N);
    else if (D == 256) agg_h<256, false><<<ab, 256, 0, stream>>>(hB, rp, csr, inv_dst, gb[s], hA, N);
    else               agg_h<128, false><<<ab, 256, 0, stream>>>(hB, rp, csr, inv_dst, gb[s], hA, N);
    h = hA;
    K = D;
  }
  // final FC: fp32 out + bias, no relu
  dim3 gf(MB, 1);
  hgemm<float><<<gf, 256, 0, stream>>>(h, wH[6], (float*)d_out, N, 128, 128, nullptr, fc_b);
}